// Round 11
// baseline (92.186 us; speedup 1.0000x reference)
//
#include <hip/hip_runtime.h>

#define NB 16
#define NL 64
#define ND 256
#define NU 500
#define NV 10000
#define MINWL 4
#define MAXWL 10
#define NWL 7
#define ITEMP 10.0f                 // 1/TEMP
#define L2I 14.4269504088896f       // 10 * log2(e)
#define NTX 1024                    // k_extract: 16 waves -> 4/SIMD
#define NWAVES 16
#define NCH 16                      // vocab chunks (grid = NB*NCH = 256 = 1/CU)
#define RSTR 501                    // dl row stride (odd -> conflict-free gathers)
#define DLPAD 32568                 // segL starts here (65*501=32565, 16B aligned)
#define SEGL_SLOTS 648
#define EXT_LDS_BYTES ((DLPAD + SEGL_SLOTS * 8) * 4)  // 151,008 B
#define NSK (NWL * 64)              // 448 (s,k) cells per batch
#define NZERO 3690.0f               // 4096 - 406 viable cells

// ================= kernel 0: stable counting sort of vocab by len =================
__global__ __launch_bounds__(512) void k_sort(const int* __restrict__ vlen,
                                              int* __restrict__ origv,
                                              int* __restrict__ bases) {
    int t = threadIdx.x;
    int lv[20];  // cached len-classes (static indexing)
#pragma unroll
    for (int j = 0; j < 20; ++j) {
        int v = t * 20 + j;
        lv[j] = (v < NV) ? (vlen[v] - MINWL) : -1;
    }
    unsigned long long hA = 0, hB = 0;  // packed u16 histograms l=0..3 / l=4..6
#pragma unroll
    for (int j = 0; j < 20; ++j) {
        int l = lv[j];
        if (l >= 0) {
            int sh = (l & 3) * 16;
            unsigned long long inc = 1ULL << sh;
            bool isA = l < 4;
            hA += isA ? inc : 0ULL;
            hB += isA ? 0ULL : inc;
        }
    }
    int lane = t & 63, wv = t >> 6;
    unsigned long long iA = hA, iB = hB;
#pragma unroll
    for (int o = 1; o < 64; o <<= 1) {
        unsigned long long a2 = (unsigned long long)__shfl_up((long long)iA, o);
        unsigned long long b2 = (unsigned long long)__shfl_up((long long)iB, o);
        if (lane >= o) { iA += a2; iB += b2; }
    }
    __shared__ unsigned long long wA[8], wB[8];
    __shared__ int base_s[8];
    if (lane == 63) { wA[wv] = iA; wB[wv] = iB; }
    __syncthreads();
    unsigned long long pA = 0, pB = 0, tA = 0, tB = 0;
#pragma unroll
    for (int w2 = 0; w2 < 8; ++w2) {
        if (w2 < wv) { pA += wA[w2]; pB += wB[w2]; }
        tA += wA[w2]; tB += wB[w2];
    }
    unsigned long long eA = pA + iA - hA, eB = pB + iB - hB;
    if (t == 0) {
        int tot[7] = {(int)(tA & 0xFFFF), (int)((tA >> 16) & 0xFFFF),
                      (int)((tA >> 32) & 0xFFFF), (int)((tA >> 48) & 0xFFFF),
                      (int)(tB & 0xFFFF), (int)((tB >> 16) & 0xFFFF),
                      (int)((tB >> 32) & 0xFFFF)};
        int run = 0;
        for (int l = 0; l < 7; ++l) { base_s[l] = run; bases[l] = run; run += tot[l]; }
        base_s[7] = run; bases[7] = run;
    }
    __syncthreads();
    unsigned long long qA = eA + ((unsigned long long)base_s[0] |
                                  ((unsigned long long)base_s[1] << 16) |
                                  ((unsigned long long)base_s[2] << 32) |
                                  ((unsigned long long)base_s[3] << 48));
    unsigned long long qB = eB + ((unsigned long long)base_s[4] |
                                  ((unsigned long long)base_s[5] << 16) |
                                  ((unsigned long long)base_s[6] << 32));
#pragma unroll
    for (int j = 0; j < 20; ++j) {  // stable: ascending v within thread
        int l = lv[j];
        if (l >= 0) {
            int sh = (l & 3) * 16;
            bool isA = l < 4;
            unsigned long long cur = isA ? qA : qB;
            int pos = (int)((cur >> sh) & 0xFFFF);
            origv[pos] = t * 20 + j;
            unsigned long long inc = 1ULL << sh;
            qA += isA ? inc : 0ULL;
            qB += isA ? 0ULL : inc;
        }
    }
}

// ========== kernel 1: dual-role — sim tiles (blk<512) + seg gather/pack (else) ==========
#define SSTR 260
#define SIM_LDS_BYTES ((2 * 32 * SSTR + 64) * 4)

__global__ __launch_bounds__(256) void k_simgather(const float* __restrict__ word,
                                                   const float* __restrict__ unit,
                                                   float* __restrict__ sim,
                                                   const int* __restrict__ origv,
                                                   const int* __restrict__ seg,
                                                   unsigned int* __restrict__ segP) {
    int blk = blockIdx.x;
    int t = threadIdx.x;
    if (blk >= 512) {  // gather role: pack sorted seg rows as u16
        int i = (blk - 512) * 256 + t;
        if (i < NV) {
            int v = origv[i];
            const int2* sp = (const int2*)(seg + v * MAXWL);
            int2 a0 = sp[0], a1 = sp[1], a2 = sp[2], a3 = sp[3], a4 = sp[4];
            unsigned int* dst = segP + i * 8;
            *(uint4*)dst = make_uint4((unsigned)(a0.x | (a0.y << 16)),
                                      (unsigned)(a1.x | (a1.y << 16)),
                                      (unsigned)(a2.x | (a2.y << 16)),
                                      (unsigned)(a3.x | (a3.y << 16)));
            dst[4] = (unsigned)(a4.x | (a4.y << 16));
        }
        return;
    }
    extern __shared__ float lds[];
    float* wt = lds;
    float* ut = lds + 32 * SSTR;
    float* scaleW = lds + 64 * SSTR;
    float* scaleU = scaleW + 32;
    int uc = blk & 15, lt = (blk >> 4) & 1, b = blk >> 5;
    int l0 = lt * 32, u0 = uc * 32;

#pragma unroll
    for (int i = 0; i < 32; ++i)
        wt[i * SSTR + t] = word[(b * NL + l0 + i) * ND + t];
#pragma unroll
    for (int i = 0; i < 32; ++i) {
        int u = u0 + i;
        ut[i * SSTR + t] = (u < NU) ? unit[u * ND + t] : 1.0f;
    }
    __syncthreads();
#pragma unroll
    for (int h = 0; h < 2; ++h) {
        int r = (t >> 4) + h * 16, p = t & 15;
        float sw = 0.f, su = 0.f;
#pragma unroll
        for (int c = 0; c < 16; ++c) {
            float x = wt[r * SSTR + p * 16 + c];
            float y = ut[r * SSTR + p * 16 + c];
            sw += x * x; su += y * y;
        }
#pragma unroll
        for (int o = 1; o < 16; o <<= 1) {
            sw += __shfl_xor(sw, o);
            su += __shfl_xor(su, o);
        }
        if (p == 0) { scaleW[r] = 1.0f / sqrtf(sw); scaleU[r] = 1.0f / sqrtf(su); }
    }
    __syncthreads();

    int lane = t & 15;
    int lp = t >> 4;
    int l = lp * 2;
    const float4* w0p = (const float4*)(wt + l * SSTR);
    const float4* w1p = (const float4*)(wt + (l + 1) * SSTR);
    const float4* x0p = (const float4*)(ut + lane * SSTR);
    const float4* x1p = (const float4*)(ut + (lane + 16) * SSTR);
    float a00 = 0.f, a01 = 0.f, a10 = 0.f, a11 = 0.f;
#pragma unroll 8
    for (int dq = 0; dq < ND / 4; ++dq) {
        float4 w0 = w0p[dq], w1 = w1p[dq], x0 = x0p[dq], x1 = x1p[dq];
        a00 += w0.x * x0.x + w0.y * x0.y + w0.z * x0.z + w0.w * x0.w;
        a01 += w0.x * x1.x + w0.y * x1.y + w0.z * x1.z + w0.w * x1.w;
        a10 += w1.x * x0.x + w1.y * x0.y + w1.z * x0.z + w1.w * x0.w;
        a11 += w1.x * x1.x + w1.y * x1.y + w1.z * x1.z + w1.w * x1.w;
    }
    float sw0 = scaleW[l], sw1 = scaleW[l + 1];
    float su0 = scaleU[lane], su1 = scaleU[lane + 16];
    int gu0 = u0 + lane, gu1 = u0 + lane + 16;
    int base = (b * NL + l0 + l) * NU;
    if (gu0 < NU) { sim[base + gu0] = a00 * (sw0 * su0); sim[base + NU + gu0] = a10 * (sw1 * su0); }
    if (gu1 < NU) { sim[base + gu1] = a01 * (sw0 * su1); sim[base + NU + gu1] = a11 * (sw1 * su1); }
}

// ========== kernel 2: transposed soft-min, all-LDS loop, fused per-b merge ==========

template <int L>
__device__ __forceinline__ void item_one(const unsigned int* __restrict__ segL,
                                         int li, const float* __restrict__ dl,
                                         const int* __restrict__ rowoff,
                                         float& Sb, float& Wb, float& mb, int& ixb,
                                         float& Sm, float& Wm, float& mmv, int& ixm) {
    const unsigned int* sp = segL + li * 8;
    uint4 p = *(const uint4*)sp;                    // uniform b128
    unsigned int w4 = (L > 8) ? sp[4] : 0u;
    unsigned int c[10];
    c[0] = p.x & 0xFFFF; c[1] = p.x >> 16;
    c[2] = p.y & 0xFFFF; c[3] = p.y >> 16;
    c[4] = p.z & 0xFFFF; c[5] = p.z >> 16;
    c[6] = p.w & 0xFFFF; c[7] = p.w >> 16;
    c[8] = w4 & 0xFFFF;  c[9] = w4 >> 16;
    float q = ((dl[rowoff[0] + c[0]] + dl[rowoff[1] + c[1]]) +
               dl[rowoff[2] + c[2]]) + dl[rowoff[3] + c[3]];
    float pm = q;
#pragma unroll
    for (int j = 4; j < L; ++j) {
        if (j == L - 1) pm = q;  // pref(L-1)
        q += dl[rowoff[j] + c[j]];
    }
    float wb = __builtin_amdgcn_exp2f(fmaf(q, -L2I, (float)L * L2I));
    Sb += wb;
    Wb = fmaf(q, wb, Wb);
    bool lb = q < mb;
    ixb = lb ? li : ixb;
    mb = lb ? q : mb;
    if constexpr (L >= 5) {  // k = L-5: ed = pref(L-1)+1, anchor L-1
        float edm = pm + 1.0f;
        float wm = __builtin_amdgcn_exp2f(fmaf(edm, -L2I, (float)(L - 1) * L2I));
        Sm += wm;
        Wm = fmaf(edm, wm, Wm);
        bool lm = edm < mmv;
        ixm = lm ? li : ixm;
        mmv = lm ? edm : mmv;
    }
}

template <int L>
__device__ __forceinline__ void bucket_passL(int a, int e, int gofs,
                                             const unsigned int* __restrict__ segL,
                                             const float* __restrict__ dl,
                                             const int* __restrict__ rowoff,
                                             float* m, float* S, float* W, int* ix) {
    if (a >= e) return;
    float Sb = 0.f, Wb = 0.f, mb = 3.0e38f;
    float Sm = 0.f, Wm = 0.f, mmv = 3.0e38f;
    int ixb = 0, ixm = 0;
    int li = a;
    for (; li + 3 < e; li += 4) {  // 4-item unroll: ~32 outstanding gathers
        item_one<L>(segL, li, dl, rowoff, Sb, Wb, mb, ixb, Sm, Wm, mmv, ixm);
        item_one<L>(segL, li + 1, dl, rowoff, Sb, Wb, mb, ixb, Sm, Wm, mmv, ixm);
        item_one<L>(segL, li + 2, dl, rowoff, Sb, Wb, mb, ixb, Sm, Wm, mmv, ixm);
        item_one<L>(segL, li + 3, dl, rowoff, Sb, Wb, mb, ixb, Sm, Wm, mmv, ixm);
    }
    for (; li < e; ++li)
        item_one<L>(segL, li, dl, rowoff, Sb, Wb, mb, ixb, Sm, Wm, mmv, ixm);

    int gb = ixb + gofs, gm_ = ixm + gofs;  // local -> global sorted index
#pragma unroll
    for (int k = 0; k < NWL; ++k) {
        if (k >= L - 4) {
            float c = (float)(k + 4 - L);
            S[k] += Sb;
            W[k] += fmaf(c, Sb, Wb);
            float cand = mb + c;  // same float op as reference's q+(float)penalty
            bool take = (cand < m[k]) || (cand == m[k] && gb < ix[k]);
            ix[k] = take ? gb : ix[k];
            m[k] = take ? cand : m[k];
        }
        if constexpr (L >= 5) {
            if (k == L - 5) {
                S[k] += Sm;
                W[k] += Wm;
                bool take = (mmv < m[k]) || (mmv == m[k] && gm_ < ix[k]);
                ix[k] = take ? gm_ : ix[k];
                m[k] = take ? mmv : m[k];
            }
        }
    }
}

__global__ __launch_bounds__(NTX, 1) void k_extract(const float* __restrict__ sim,
                                                    const unsigned int* __restrict__ segP,
                                                    const int* __restrict__ basesG,
                                                    const int* __restrict__ origv,
                                                    float* __restrict__ pM,
                                                    float* __restrict__ pS,
                                                    float* __restrict__ pW,
                                                    int* __restrict__ pI,
                                                    unsigned int* __restrict__ cnt,
                                                    float* __restrict__ out) {
    extern __shared__ float dl[];  // [65][RSTR] then segL
    unsigned int* segL = (unsigned int*)(dl + DLPAD);
    int blk = blockIdx.x;          // b*NCH + ch
    int ch = blk & (NCH - 1), b = blk >> 4;
    int t = threadIdx.x;
    int s = t & 63, w = t >> 6;    // w in 0..15

    // block-level bucket slices + local LDS bases
    int cs[7], ne[7], lb[7];
    {
        int run = 0;
#pragma unroll
        for (int l = 0; l < 7; ++l) {
            int lo = basesG[l], hi = basesG[l + 1];
            int n = hi - lo;
            int pc = (n + NCH - 1) >> 4;
            int c0 = lo + ch * pc;
            int c1 = min(c0 + pc, hi);
            cs[l] = c0;
            ne[l] = max(c1 - c0, 0);
            lb[l] = run;
            run += ne[l];
        }
    }

    // stage d = 1 - sim (rows 0..63) + zero row 64
    {
        const float2* simq = (const float2*)(sim + b * NL * NU);
        for (int idx = t; idx < NL * 250; idx += NTX) {
            int r = idx / 250;
            int u2 = idx - r * 250;
            float2 g = simq[idx];
            float* ds = dl + r * RSTR + u2 * 2;
            ds[0] = 1.0f - g.x;
            ds[1] = 1.0f - g.y;
        }
        if (t < NU + 1) dl[64 * RSTR + t] = 0.0f;
    }
    // stage packed seg rows for this block's 7 ranges
#pragma unroll
    for (int l = 0; l < 7; ++l) {
        for (int ii = t; ii < ne[l]; ii += NTX) {
            const unsigned int* gp = segP + (cs[l] + ii) * 8;
            uint4 pv = *(const uint4*)gp;
            unsigned int w4 = gp[4];
            unsigned int* dp = segL + (lb[l] + ii) * 8;
            *(uint4*)dp = pv;
            dp[4] = w4;
        }
    }
    __syncthreads();

    int rowoff[10];
#pragma unroll
    for (int j = 0; j < 10; ++j) rowoff[j] = min(s + j, 64) * RSTR;

    float m[NWL], S[NWL], W[NWL];
    int ix[NWL];
#pragma unroll
    for (int k = 0; k < NWL; ++k) { m[k] = 3.0e38f; S[k] = 0.f; W[k] = 0.f; ix[k] = 0; }

    int la[7], le[7];
#pragma unroll
    for (int l = 0; l < 7; ++l) {
        int pw = (ne[l] + NWAVES - 1) >> 4;
        la[l] = lb[l] + w * pw;
        le[l] = min(la[l] + pw, lb[l] + ne[l]);
    }
    bucket_passL<4>(la[0], le[0], cs[0] - lb[0], segL, dl, rowoff, m, S, W, ix);
    bucket_passL<5>(la[1], le[1], cs[1] - lb[1], segL, dl, rowoff, m, S, W, ix);
    bucket_passL<6>(la[2], le[2], cs[2] - lb[2], segL, dl, rowoff, m, S, W, ix);
    bucket_passL<7>(la[3], le[3], cs[3] - lb[3], segL, dl, rowoff, m, S, W, ix);
    bucket_passL<8>(la[4], le[4], cs[4] - lb[4], segL, dl, rowoff, m, S, W, ix);
    bucket_passL<9>(la[5], le[5], cs[5] - lb[5], segL, dl, rowoff, m, S, W, ix);
    bucket_passL<10>(la[6], le[6], cs[6] - lb[6], segL, dl, rowoff, m, S, W, ix);

    // cross-wave merge via LDS (dl/segL dead now)
    __syncthreads();
    float* scrM = dl;                        // [16][NWL][64]
    float* scrS = dl + NWAVES * NSK;
    float* scrW = dl + 2 * NWAVES * NSK;
    int* scrI = (int*)(dl + 3 * NWAVES * NSK);
#pragma unroll
    for (int k = 0; k < NWL; ++k) {
        int o = (w * NWL + k) * 64 + s;
        scrM[o] = m[k]; scrS[o] = S[k]; scrW[o] = W[k]; scrI[o] = ix[k];
    }
    __syncthreads();
    if (t < NSK) {
        int k = t >> 6, ss = t & 63;
        int o0 = k * 64 + ss;
        float mm = scrM[o0], SS = scrS[o0], WW = scrW[o0];
        int II = scrI[o0];
#pragma unroll
        for (int w2 = 1; w2 < NWAVES; ++w2) {
            int o = (w2 * NWL + k) * 64 + ss;
            float m2 = scrM[o];
            int i2 = scrI[o];
            bool take = (m2 < mm) || (m2 == mm && i2 < II);
            II = take ? i2 : II;
            mm = take ? m2 : mm;
            SS += scrS[o];
            WW += scrW[o];
        }
        int off = (b * NCH + ch) * NSK + t;
        pM[off] = mm; pS[off] = SS; pW[off] = WW; pI[off] = II;
    }

    // -------- fused per-b merge: last-arriving chunk block does it --------
    __syncthreads();  // barrier drains all waves' global stores (vmcnt 0)
    __shared__ int lastFlag;
    if (t == 0) {
        __threadfence();  // device-scope visibility of this block's partials
        unsigned prev = __hip_atomic_fetch_add(&cnt[b], 1u, __ATOMIC_ACQ_REL,
                                               __HIP_MEMORY_SCOPE_AGENT);
        lastFlag = (prev == NCH - 1);
    }
    __syncthreads();
    if (!lastFlag) return;

    // merge NCH chunk partials (fixed order -> deterministic), score, outputs
    float* score = dl;            // [NSK]
    int* ixf = (int*)(dl + NSK);  // [NSK]
    float* rm = dl + 2 * NSK;     // [16] x4
    float* rS = rm + 16;
    float* rW = rS + 16;
    int* rX = (int*)(rW + 16);
    __shared__ float gm;
    __shared__ int gfl;

    float x = -1.0f;
    int fl = 0x7FFFFFFF;
    if (t < NSK) {
        int base = b * NCH * NSK + t;
        float mm = pM[base], SS = pS[base], WW = pW[base];
        int II = pI[base];
        for (int c = 1; c < NCH; ++c) {
            int o = base + c * NSK;
            float m2 = pM[o];
            int i2 = pI[o];
            bool take = (m2 < mm) || (m2 == mm && i2 < II);
            II = take ? i2 : II;
            mm = take ? m2 : mm;
            SS += pS[o];
            WW += pW[o];
        }
        int k = t >> 6, ss = t & 63;
        int kmax = min(NWL - 1, 60 - ss);  // negative for ss > 60
        if (k <= kmax) {
            float med = WW / SS;
            float wl = (float)(MINWL + k);
            float z = 1.0f - 2.0f * (med / wl);
            float cel = (z > 0.f) ? z : (__expf(z) - 1.0f);  // celu
            x = 0.5f * (cel + 1.0f) * wl;
            ixf[t] = II;
            fl = ss * 64 + (ss + k + 3);
        }
        score[t] = (k <= kmax) ? x : 0.0f;
    }
    __syncthreads();

    // block argmax (first flat index on ties)
    float mv = x;
    int mf = fl;
#pragma unroll
    for (int o = 32; o >= 1; o >>= 1) {
        float m2 = __shfl_down(mv, o);
        int f2 = __shfl_down(mf, o);
        bool take = (m2 > mv) || (m2 == mv && f2 < mf);
        mv = take ? m2 : mv;
        mf = take ? f2 : mf;
    }
    if ((t & 63) == 0) { rm[w] = mv; rX[w] = mf; }
    __syncthreads();
    if (t == 0) {
        float mm = rm[0];
        int ff = rX[0];
#pragma unroll
        for (int w2 = 1; w2 < NWAVES; ++w2) {
            bool take = (rm[w2] > mm) || (rm[w2] == mm && rX[w2] < ff);
            mm = take ? rm[w2] : mm;
            ff = take ? rX[w2] : ff;
        }
        gm = mm; gfl = ff;
    }
    __syncthreads();
    float M = gm;

    float Sl = 0.f, Wl = 0.f;
    if (x >= 0.0f) {
        float wq = __expf((x - M) * ITEMP);
        Sl = wq;
        Wl = x * wq;
    }
#pragma unroll
    for (int o = 32; o >= 1; o >>= 1) {
        Sl += __shfl_down(Sl, o);
        Wl += __shfl_down(Wl, o);
    }
    if ((t & 63) == 0) { rS[w] = Sl; rW[w] = Wl; }
    __syncthreads();
    if (t == 0) {
        float SS = 0.f, WW = 0.f;
#pragma unroll
        for (int w2 = 0; w2 < NWAVES; ++w2) { SS += rS[w2]; WW += rW[w2]; }
        SS += NZERO * __expf(-M * ITEMP);  // zero cells' mass
        float best = WW / SS;
        int st = gfl >> 6, en = gfl & 63;
        int ks = en - st - 3;
        int II = ixf[ks * 64 + st];
        out[b] = (float)st;
        out[NB + b] = (float)en;
        out[2 * NB + b] = best;
        out[3 * NB + b] = (float)origv[II];
    }

    float* dense = out + 4 * NB + b * NL * NL;
    for (int f = t; f < NL * NL; f += NTX) {
        int ss = f >> 6, ee = f & 63;
        int k = ee - ss - 3;
        dense[f] = (k >= 0 && k < NWL) ? score[k * 64 + ss] : 0.0f;
    }
}

extern "C" void kernel_launch(void* const* d_in, const int* in_sizes, int n_in,
                              void* d_out, int out_size, void* d_ws, size_t ws_size,
                              hipStream_t stream) {
    const float* word = (const float*)d_in[0];  // (B,L,D) f32
    const float* unit = (const float*)d_in[1];  // (U,D) f32
    const int* seg = (const int*)d_in[2];       // (V,MAXWL) i32
    const int* vlen = (const int*)d_in[3];      // (V,) i32
    float* out = (float*)d_out;                 // [start|end|score|vocab|dense]
    char* ws = (char*)d_ws;
    float* sim = (float*)ws;                    // 2,048,000 B
    int* origv = (int*)(ws + 2048000);          // 40,000 B
    int* bases = (int*)(ws + 2088000);          // 32 B
    unsigned int* segP = (unsigned int*)(ws + 2088032);  // 320,000 B
    float* pM = (float*)(ws + 2408032);         // 458,752 B each
    float* pS = (float*)(ws + 2866784);
    float* pW = (float*)(ws + 3325536);
    int* pI = (int*)(ws + 3784288);
    unsigned int* cnt = (unsigned int*)(ws + 4243040);  // 64 B

    hipFuncSetAttribute((const void*)k_simgather,
                        hipFuncAttributeMaxDynamicSharedMemorySize, SIM_LDS_BYTES);
    hipFuncSetAttribute((const void*)k_extract,
                        hipFuncAttributeMaxDynamicSharedMemorySize, EXT_LDS_BYTES);

    hipMemsetAsync(cnt, 0, NB * sizeof(unsigned int), stream);
    k_sort<<<1, 512, 0, stream>>>(vlen, origv, bases);
    k_simgather<<<512 + 40, 256, SIM_LDS_BYTES, stream>>>(word, unit, sim,
                                                          origv, seg, segP);
    k_extract<<<NB * NCH, NTX, EXT_LDS_BYTES, stream>>>(sim, segP, bases, origv,
                                                        pM, pS, pW, pI, cnt, out);
}

// Round 12
// 71.036 us; speedup vs baseline: 1.2977x; 1.2977x over previous
//
#include <hip/hip_runtime.h>

#define NB 16
#define NL 64
#define ND 256
#define NU 500
#define NV 10000
#define MINWL 4
#define MAXWL 10
#define NWL 7
#define ITEMP 10.0f                 // 1/TEMP
#define L2I 14.4269504088896f       // 10 * log2(e)
#define NT 512
#define NTX 1024                    // k_extract: 16 waves -> 4/SIMD
#define NWAVES 16
#define NCH 16                      // vocab chunks (grid = NB*NCH = 256 = 1/CU)
#define RSTR 501                    // dl row stride (odd -> conflict-free gathers)
#define DLPAD 32568                 // segL starts here (65*501=32565, 16B aligned)
#define SEGL_SLOTS 648
#define EXT_LDS_BYTES ((DLPAD + SEGL_SLOTS * 8) * 4)  // 151,008 B
#define NSK (NWL * 64)              // 448 (s,k) cells per batch
#define NZERO 3690.0f               // 4096 - 406 viable cells

// ========== kernel 0: dual-role — sim tiles (blk<512) + vocab len-sort (blk==512) ==========
// sort and sim are data-independent; fusing hides the 1-block sort under sim.
#define SSTR 260
#define SIM_LDS_BYTES ((2 * 32 * SSTR + 64) * 4)

__global__ __launch_bounds__(256) void k_sortsim(const float* __restrict__ word,
                                                 const float* __restrict__ unit,
                                                 float* __restrict__ sim,
                                                 const int* __restrict__ vlen,
                                                 int* __restrict__ origv,
                                                 int* __restrict__ bases) {
    int blk = blockIdx.x;
    int t = threadIdx.x;
    if (blk == 512) {  // ---- sort role: stable counting sort by len (256 thr) ----
        const int CH = 40;  // 256*40 >= NV
        int lo = t * CH, hi = min(lo + CH, NV);
        unsigned long long hA = 0, hB = 0;  // packed u16 histograms l=0..3 / 4..6
        for (int v = lo; v < hi; ++v) {
            int l = vlen[v] - MINWL;
            int sh = (l & 3) * 16;
            unsigned long long inc = 1ULL << sh;
            bool isA = l < 4;
            hA += isA ? inc : 0ULL;
            hB += isA ? 0ULL : inc;
        }
        int lane = t & 63, wv = t >> 6;  // 4 waves
        unsigned long long iA = hA, iB = hB;
#pragma unroll
        for (int o = 1; o < 64; o <<= 1) {
            unsigned long long a2 = (unsigned long long)__shfl_up((long long)iA, o);
            unsigned long long b2 = (unsigned long long)__shfl_up((long long)iB, o);
            if (lane >= o) { iA += a2; iB += b2; }
        }
        __shared__ unsigned long long wA[4], wB[4];
        __shared__ int base_s[8];
        if (lane == 63) { wA[wv] = iA; wB[wv] = iB; }
        __syncthreads();
        unsigned long long pA = 0, pB = 0, tA = 0, tB = 0;
#pragma unroll
        for (int w2 = 0; w2 < 4; ++w2) {
            if (w2 < wv) { pA += wA[w2]; pB += wB[w2]; }
            tA += wA[w2]; tB += wB[w2];
        }
        unsigned long long eA = pA + iA - hA, eB = pB + iB - hB;  // exclusive
        if (t == 0) {
            int tot[7] = {(int)(tA & 0xFFFF), (int)((tA >> 16) & 0xFFFF),
                          (int)((tA >> 32) & 0xFFFF), (int)((tA >> 48) & 0xFFFF),
                          (int)(tB & 0xFFFF), (int)((tB >> 16) & 0xFFFF),
                          (int)((tB >> 32) & 0xFFFF)};
            int run = 0;
            for (int l = 0; l < 7; ++l) { base_s[l] = run; bases[l] = run; run += tot[l]; }
            base_s[7] = run; bases[7] = run;
        }
        __syncthreads();
        unsigned long long qA = eA + ((unsigned long long)base_s[0] |
                                      ((unsigned long long)base_s[1] << 16) |
                                      ((unsigned long long)base_s[2] << 32) |
                                      ((unsigned long long)base_s[3] << 48));
        unsigned long long qB = eB + ((unsigned long long)base_s[4] |
                                      ((unsigned long long)base_s[5] << 16) |
                                      ((unsigned long long)base_s[6] << 32));
        for (int v = lo; v < hi; ++v) {  // stable: ascending v within thread
            int l = vlen[v] - MINWL;
            int sh = (l & 3) * 16;
            bool isA = l < 4;
            unsigned long long cur = isA ? qA : qB;
            int pos = (int)((cur >> sh) & 0xFFFF);
            origv[pos] = v;
            unsigned long long inc = 1ULL << sh;
            qA += isA ? inc : 0ULL;
            qB += isA ? 0ULL : inc;
        }
        return;
    }
    // ---- sim role: sim = normalize(word) @ normalize(unit)^T ----
    extern __shared__ float lds[];
    float* wt = lds;
    float* ut = lds + 32 * SSTR;
    float* scaleW = lds + 64 * SSTR;
    float* scaleU = scaleW + 32;
    int uc = blk & 15, lt = (blk >> 4) & 1, b = blk >> 5;
    int l0 = lt * 32, u0 = uc * 32;

#pragma unroll
    for (int i = 0; i < 32; ++i)
        wt[i * SSTR + t] = word[(b * NL + l0 + i) * ND + t];
#pragma unroll
    for (int i = 0; i < 32; ++i) {
        int u = u0 + i;
        ut[i * SSTR + t] = (u < NU) ? unit[u * ND + t] : 1.0f;
    }
    __syncthreads();
#pragma unroll
    for (int h = 0; h < 2; ++h) {
        int r = (t >> 4) + h * 16, p = t & 15;
        float sw = 0.f, su = 0.f;
#pragma unroll
        for (int c = 0; c < 16; ++c) {
            float x = wt[r * SSTR + p * 16 + c];
            float y = ut[r * SSTR + p * 16 + c];
            sw += x * x; su += y * y;
        }
#pragma unroll
        for (int o = 1; o < 16; o <<= 1) {
            sw += __shfl_xor(sw, o);
            su += __shfl_xor(su, o);
        }
        if (p == 0) { scaleW[r] = 1.0f / sqrtf(sw); scaleU[r] = 1.0f / sqrtf(su); }
    }
    __syncthreads();

    int lane = t & 15;
    int lp = t >> 4;
    int l = lp * 2;
    const float4* w0p = (const float4*)(wt + l * SSTR);
    const float4* w1p = (const float4*)(wt + (l + 1) * SSTR);
    const float4* x0p = (const float4*)(ut + lane * SSTR);
    const float4* x1p = (const float4*)(ut + (lane + 16) * SSTR);
    float a00 = 0.f, a01 = 0.f, a10 = 0.f, a11 = 0.f;
#pragma unroll 8
    for (int dq = 0; dq < ND / 4; ++dq) {
        float4 w0 = w0p[dq], w1 = w1p[dq], x0 = x0p[dq], x1 = x1p[dq];
        a00 += w0.x * x0.x + w0.y * x0.y + w0.z * x0.z + w0.w * x0.w;
        a01 += w0.x * x1.x + w0.y * x1.y + w0.z * x1.z + w0.w * x1.w;
        a10 += w1.x * x0.x + w1.y * x0.y + w1.z * x0.z + w1.w * x0.w;
        a11 += w1.x * x1.x + w1.y * x1.y + w1.z * x1.z + w1.w * x1.w;
    }
    float sw0 = scaleW[l], sw1 = scaleW[l + 1];
    float su0 = scaleU[lane], su1 = scaleU[lane + 16];
    int gu0 = u0 + lane, gu1 = u0 + lane + 16;
    int base = (b * NL + l0 + l) * NU;
    if (gu0 < NU) { sim[base + gu0] = a00 * (sw0 * su0); sim[base + NU + gu0] = a10 * (sw1 * su0); }
    if (gu1 < NU) { sim[base + gu1] = a01 * (sw0 * su1); sim[base + NU + gu1] = a11 * (sw1 * su1); }
}

// ========== kernel 0b: gather seg rows into sorted u16-packed rows (wide) ==========
__global__ __launch_bounds__(256) void k_gather(const int* __restrict__ origv,
                                                const int* __restrict__ seg,
                                                unsigned int* __restrict__ segP) {
    int i = blockIdx.x * 256 + threadIdx.x;
    if (i >= NV) return;
    int v = origv[i];
    const int2* sp = (const int2*)(seg + v * MAXWL);
    int2 a0 = sp[0], a1 = sp[1], a2 = sp[2], a3 = sp[3], a4 = sp[4];
    unsigned int* dst = segP + i * 8;
    *(uint4*)dst = make_uint4((unsigned)(a0.x | (a0.y << 16)),
                              (unsigned)(a1.x | (a1.y << 16)),
                              (unsigned)(a2.x | (a2.y << 16)),
                              (unsigned)(a3.x | (a3.y << 16)));
    dst[4] = (unsigned)(a4.x | (a4.y << 16));
}

// ========== kernel 2: transposed soft-min — all-LDS main loop (R10 verbatim) ==========

template <int L>
__device__ __forceinline__ void item_one(const unsigned int* __restrict__ segL,
                                         int li, const float* __restrict__ dl,
                                         const int* __restrict__ rowoff,
                                         float& Sb, float& Wb, float& mb, int& ixb,
                                         float& Sm, float& Wm, float& mmv, int& ixm) {
    const unsigned int* sp = segL + li * 8;
    uint4 p = *(const uint4*)sp;                    // uniform b128
    unsigned int w4 = (L > 8) ? sp[4] : 0u;          // uniform b32 (L=9,10 only)
    unsigned int c[10];
    c[0] = p.x & 0xFFFF; c[1] = p.x >> 16;
    c[2] = p.y & 0xFFFF; c[3] = p.y >> 16;
    c[4] = p.z & 0xFFFF; c[5] = p.z >> 16;
    c[6] = p.w & 0xFFFF; c[7] = p.w >> 16;
    c[8] = w4 & 0xFFFF;  c[9] = w4 >> 16;
    float q = ((dl[rowoff[0] + c[0]] + dl[rowoff[1] + c[1]]) +
               dl[rowoff[2] + c[2]]) + dl[rowoff[3] + c[3]];
    float pm = q;
#pragma unroll
    for (int j = 4; j < L; ++j) {
        if (j == L - 1) pm = q;  // pref(L-1)
        q += dl[rowoff[j] + c[j]];
    }
    float wb = __builtin_amdgcn_exp2f(fmaf(q, -L2I, (float)L * L2I));
    Sb += wb;
    Wb = fmaf(q, wb, Wb);
    bool lb = q < mb;
    ixb = lb ? li : ixb;
    mb = lb ? q : mb;
    if constexpr (L >= 5) {  // k = L-5: ed = pref(L-1)+1, anchor L-1
        float edm = pm + 1.0f;
        float wm = __builtin_amdgcn_exp2f(fmaf(edm, -L2I, (float)(L - 1) * L2I));
        Sm += wm;
        Wm = fmaf(edm, wm, Wm);
        bool lm = edm < mmv;
        ixm = lm ? li : ixm;
        mmv = lm ? edm : mmv;
    }
}

template <int L>
__device__ __forceinline__ void bucket_passL(int a, int e, int gofs,
                                             const unsigned int* __restrict__ segL,
                                             const float* __restrict__ dl,
                                             const int* __restrict__ rowoff,
                                             float* m, float* S, float* W, int* ix) {
    if (a >= e) return;
    float Sb = 0.f, Wb = 0.f, mb = 3.0e38f;
    float Sm = 0.f, Wm = 0.f, mmv = 3.0e38f;
    int ixb = 0, ixm = 0;
    int li = a;
    for (; li + 1 < e; li += 2) {  // 2-item unroll (R10-proven: VGPR stays sane)
        item_one<L>(segL, li, dl, rowoff, Sb, Wb, mb, ixb, Sm, Wm, mmv, ixm);
        item_one<L>(segL, li + 1, dl, rowoff, Sb, Wb, mb, ixb, Sm, Wm, mmv, ixm);
    }
    if (li < e)
        item_one<L>(segL, li, dl, rowoff, Sb, Wb, mb, ixb, Sm, Wm, mmv, ixm);

    int gb = ixb + gofs, gm_ = ixm + gofs;  // local -> global sorted index
#pragma unroll
    for (int k = 0; k < NWL; ++k) {
        if (k >= L - 4) {
            float c = (float)(k + 4 - L);
            S[k] += Sb;
            W[k] += fmaf(c, Sb, Wb);
            float cand = mb + c;  // same float op as reference's q+(float)penalty
            bool take = (cand < m[k]) || (cand == m[k] && gb < ix[k]);
            ix[k] = take ? gb : ix[k];
            m[k] = take ? cand : m[k];
        }
        if constexpr (L >= 5) {
            if (k == L - 5) {
                S[k] += Sm;
                W[k] += Wm;
                bool take = (mmv < m[k]) || (mmv == m[k] && gm_ < ix[k]);
                ix[k] = take ? gm_ : ix[k];
                m[k] = take ? mmv : m[k];
            }
        }
    }
}

__global__ __launch_bounds__(NTX, 1) void k_extract(const float* __restrict__ sim,
                                                    const unsigned int* __restrict__ segP,
                                                    const int* __restrict__ basesG,
                                                    float* __restrict__ pM,
                                                    float* __restrict__ pS,
                                                    float* __restrict__ pW,
                                                    int* __restrict__ pI) {
    extern __shared__ float dl[];  // [65][RSTR] then segL
    unsigned int* segL = (unsigned int*)(dl + DLPAD);
    int blk = blockIdx.x;          // b*NCH + ch
    int ch = blk & (NCH - 1), b = blk >> 4;
    int t = threadIdx.x;
    int s = t & 63, w = t >> 6;    // w in 0..15

    // block-level bucket slices + local LDS bases
    int cs[7], ne[7], lb[7];
    {
        int run = 0;
#pragma unroll
        for (int l = 0; l < 7; ++l) {
            int lo = basesG[l], hi = basesG[l + 1];
            int n = hi - lo;
            int pc = (n + NCH - 1) >> 4;
            int c0 = lo + ch * pc;
            int c1 = min(c0 + pc, hi);
            cs[l] = c0;
            ne[l] = max(c1 - c0, 0);
            lb[l] = run;
            run += ne[l];
        }
    }

    // stage d = 1 - sim (rows 0..63) + zero row 64
    {
        const float2* simq = (const float2*)(sim + b * NL * NU);
        for (int idx = t; idx < NL * 250; idx += NTX) {
            int r = idx / 250;
            int u2 = idx - r * 250;
            float2 g = simq[idx];
            float* ds = dl + r * RSTR + u2 * 2;
            ds[0] = 1.0f - g.x;
            ds[1] = 1.0f - g.y;
        }
        if (t < NU + 1) dl[64 * RSTR + t] = 0.0f;
    }
    // stage packed seg rows for this block's 7 ranges
#pragma unroll
    for (int l = 0; l < 7; ++l) {
        for (int ii = t; ii < ne[l]; ii += NTX) {
            const unsigned int* gp = segP + (cs[l] + ii) * 8;
            uint4 pv = *(const uint4*)gp;
            unsigned int w4 = gp[4];
            unsigned int* dp = segL + (lb[l] + ii) * 8;
            *(uint4*)dp = pv;
            dp[4] = w4;
        }
    }
    __syncthreads();

    int rowoff[10];
#pragma unroll
    for (int j = 0; j < 10; ++j) rowoff[j] = min(s + j, 64) * RSTR;

    float m[NWL], S[NWL], W[NWL];
    int ix[NWL];
#pragma unroll
    for (int k = 0; k < NWL; ++k) { m[k] = 3.0e38f; S[k] = 0.f; W[k] = 0.f; ix[k] = 0; }

    int la[7], le[7];
#pragma unroll
    for (int l = 0; l < 7; ++l) {
        int pw = (ne[l] + NWAVES - 1) >> 4;
        la[l] = lb[l] + w * pw;
        le[l] = min(la[l] + pw, lb[l] + ne[l]);
    }
    bucket_passL<4>(la[0], le[0], cs[0] - lb[0], segL, dl, rowoff, m, S, W, ix);
    bucket_passL<5>(la[1], le[1], cs[1] - lb[1], segL, dl, rowoff, m, S, W, ix);
    bucket_passL<6>(la[2], le[2], cs[2] - lb[2], segL, dl, rowoff, m, S, W, ix);
    bucket_passL<7>(la[3], le[3], cs[3] - lb[3], segL, dl, rowoff, m, S, W, ix);
    bucket_passL<8>(la[4], le[4], cs[4] - lb[4], segL, dl, rowoff, m, S, W, ix);
    bucket_passL<9>(la[5], le[5], cs[5] - lb[5], segL, dl, rowoff, m, S, W, ix);
    bucket_passL<10>(la[6], le[6], cs[6] - lb[6], segL, dl, rowoff, m, S, W, ix);

    // cross-wave merge via LDS (dl/segL dead now); 16 partial sets = 114.7KB
    __syncthreads();
    float* scrM = dl;                        // [16][NWL][64]
    float* scrS = dl + NWAVES * NSK;
    float* scrW = dl + 2 * NWAVES * NSK;
    int* scrI = (int*)(dl + 3 * NWAVES * NSK);
#pragma unroll
    for (int k = 0; k < NWL; ++k) {
        int o = (w * NWL + k) * 64 + s;
        scrM[o] = m[k]; scrS[o] = S[k]; scrW[o] = W[k]; scrI[o] = ix[k];
    }
    __syncthreads();
    if (t < NSK) {
        int k = t >> 6, ss = t & 63;
        int o0 = k * 64 + ss;
        float mm = scrM[o0], SS = scrS[o0], WW = scrW[o0];
        int II = scrI[o0];
#pragma unroll
        for (int w2 = 1; w2 < NWAVES; ++w2) {
            int o = (w2 * NWL + k) * 64 + ss;
            float m2 = scrM[o];
            int i2 = scrI[o];
            bool take = (m2 < mm) || (m2 == mm && i2 < II);
            II = take ? i2 : II;
            mm = take ? m2 : mm;
            SS += scrS[o];
            WW += scrW[o];
        }
        int off = (b * NCH + ch) * NSK + t;
        pM[off] = mm; pS[off] = SS; pW[off] = WW; pI[off] = II;
    }
}

// ========== kernel 3: merge chunks, scores, dense, span softmax, outputs ==========
__global__ __launch_bounds__(NT) void k_merge(const float* __restrict__ pM,
                                              const float* __restrict__ pS,
                                              const float* __restrict__ pW,
                                              const int* __restrict__ pI,
                                              const int* __restrict__ origv,
                                              float* __restrict__ out) {
    int b = blockIdx.x, t = threadIdx.x;
    __shared__ float score[NSK];
    __shared__ int ixf[NSK];
    __shared__ float rm[8], rS[8], rW[8];
    __shared__ int rX[8];
    __shared__ float gm;
    __shared__ int gfl;

    float x = -1.0f;  // invalid marker (valid scores are strictly > 0)
    int fl = 0x7FFFFFFF;
    if (t < NSK) {
        int base = b * NCH * NSK + t;
        float mm = pM[base], SS = pS[base], WW = pW[base];
        int II = pI[base];
        for (int c = 1; c < NCH; ++c) {
            int o = base + c * NSK;
            float m2 = pM[o];
            int i2 = pI[o];
            bool take = (m2 < mm) || (m2 == mm && i2 < II);
            II = take ? i2 : II;
            mm = take ? m2 : mm;
            SS += pS[o];
            WW += pW[o];
        }
        int k = t >> 6, ss = t & 63;
        int kmax = min(NWL - 1, 60 - ss);  // negative for ss > 60
        if (k <= kmax) {
            float med = WW / SS;
            float wl = (float)(MINWL + k);
            float z = 1.0f - 2.0f * (med / wl);
            float cel = (z > 0.f) ? z : (__expf(z) - 1.0f);  // celu
            x = 0.5f * (cel + 1.0f) * wl;
            ixf[t] = II;
            fl = ss * 64 + (ss + k + 3);  // flat dense index
        }
        score[t] = (k <= kmax) ? x : 0.0f;
    }
    __syncthreads();

    // block argmax (first flat index on ties)
    float mv = x;
    int mf = fl;
#pragma unroll
    for (int o = 32; o >= 1; o >>= 1) {
        float m2 = __shfl_down(mv, o);
        int f2 = __shfl_down(mf, o);
        bool take = (m2 > mv) || (m2 == mv && f2 < mf);
        mv = take ? m2 : mv;
        mf = take ? f2 : mf;
    }
    if ((t & 63) == 0) { rm[t >> 6] = mv; rX[t >> 6] = mf; }
    __syncthreads();
    if (t == 0) {
        float mm = rm[0];
        int ff = rX[0];
#pragma unroll
        for (int w2 = 1; w2 < 8; ++w2) {
            bool take = (rm[w2] > mm) || (rm[w2] == mm && rX[w2] < ff);
            mm = take ? rm[w2] : mm;
            ff = take ? rX[w2] : ff;
        }
        gm = mm; gfl = ff;
    }
    __syncthreads();
    float M = gm;

    // soft-max sums over the 406 candidates + closed-form zero mass
    float Sl = 0.f, Wl = 0.f;
    if (x >= 0.0f) {
        float wq = __expf((x - M) * ITEMP);
        Sl = wq;
        Wl = x * wq;
    }
#pragma unroll
    for (int o = 32; o >= 1; o >>= 1) {
        Sl += __shfl_down(Sl, o);
        Wl += __shfl_down(Wl, o);
    }
    if ((t & 63) == 0) { rS[t >> 6] = Sl; rW[t >> 6] = Wl; }
    __syncthreads();
    if (t == 0) {
        float SS = 0.f, WW = 0.f;
#pragma unroll
        for (int w2 = 0; w2 < 8; ++w2) { SS += rS[w2]; WW += rW[w2]; }
        SS += NZERO * __expf(-M * ITEMP);  // zero cells' mass (W contribution is 0)
        float best = WW / SS;
        int st = gfl >> 6, en = gfl & 63;
        int ks = en - st - 3;  // winner is always a viable cell -> 0..6
        int II = ixf[ks * 64 + st];
        out[b] = (float)st;
        out[NB + b] = (float)en;
        out[2 * NB + b] = best;
        out[3 * NB + b] = (float)origv[II];
    }

    // dense output
    float* dense = out + 4 * NB + b * NL * NL;
    for (int f = t; f < NL * NL; f += NT) {
        int ss = f >> 6, ee = f & 63;
        int k = ee - ss - 3;
        dense[f] = (k >= 0 && k < NWL) ? score[k * 64 + ss] : 0.0f;
    }
}

extern "C" void kernel_launch(void* const* d_in, const int* in_sizes, int n_in,
                              void* d_out, int out_size, void* d_ws, size_t ws_size,
                              hipStream_t stream) {
    const float* word = (const float*)d_in[0];  // (B,L,D) f32
    const float* unit = (const float*)d_in[1];  // (U,D) f32
    const int* seg = (const int*)d_in[2];       // (V,MAXWL) i32
    const int* vlen = (const int*)d_in[3];      // (V,) i32
    float* out = (float*)d_out;                 // [start|end|score|vocab|dense]
    char* ws = (char*)d_ws;
    float* sim = (float*)ws;                    // 2,048,000 B
    int* origv = (int*)(ws + 2048000);          // 40,000 B
    int* bases = (int*)(ws + 2088000);          // 32 B
    unsigned int* segP = (unsigned int*)(ws + 2088032);  // 320,000 B
    float* pM = (float*)(ws + 2408032);         // 458,752 B each
    float* pS = (float*)(ws + 2866784);
    float* pW = (float*)(ws + 3325536);
    int* pI = (int*)(ws + 3784288);

    hipFuncSetAttribute((const void*)k_sortsim,
                        hipFuncAttributeMaxDynamicSharedMemorySize, SIM_LDS_BYTES);
    hipFuncSetAttribute((const void*)k_extract,
                        hipFuncAttributeMaxDynamicSharedMemorySize, EXT_LDS_BYTES);

    k_sortsim<<<513, 256, SIM_LDS_BYTES, stream>>>(word, unit, sim, vlen, origv, bases);
    k_gather<<<(NV + 255) / 256, 256, 0, stream>>>(origv, seg, segP);
    k_extract<<<NB * NCH, NTX, EXT_LDS_BYTES, stream>>>(sim, segP, bases, pM, pS, pW, pI);
    k_merge<<<NB, NT, 0, stream>>>(pM, pS, pW, pI, origv, out);
}

// Round 13
// 61.228 us; speedup vs baseline: 1.5056x; 1.1602x over previous
//
#include <hip/hip_runtime.h>

#define NB 16
#define NL 64
#define ND 256
#define NU 500
#define NV 10000
#define MINWL 4
#define MAXWL 10
#define NWL 7
#define ITEMP 10.0f                 // 1/TEMP
#define L2I 14.4269504088896f       // 10 * log2(e)
#define NT 512
#define NTX 1024                    // k_extract: 16 waves -> 4/SIMD
#define NWAVES 16
#define NCH 16                      // vocab chunks (grid = NB*NCH = 256 = 1/CU)
#define RSTR 501                    // dl row stride (odd -> conflict-free gathers)
#define DLPAD 32568                 // segL starts here (65*501=32565, 16B aligned)
#define SEGL_SLOTS 648
#define EXT_LDS_BYTES ((DLPAD + SEGL_SLOTS * 8) * 4)  // 151,008 B
#define NSK (NWL * 64)              // 448 (s,k) cells per batch
#define NZERO 3690.0f               // 4096 - 406 viable cells

// ================= kernel 0: stable counting sort of vocab by len =================
// Register-cached: 5x int4 loads issued together (one latency window), both
// passes run from registers. t<500 covers exactly NV = 500*20.
__global__ __launch_bounds__(512) void k_sort(const int* __restrict__ vlen,
                                              int* __restrict__ origv,
                                              int* __restrict__ bases) {
    int t = threadIdx.x;
    int lv[20];
    if (t < 500) {
        const int4* vp = (const int4*)(vlen + t * 20);
        int4 q0 = vp[0], q1 = vp[1], q2 = vp[2], q3 = vp[3], q4 = vp[4];
        int raw[20] = {q0.x, q0.y, q0.z, q0.w, q1.x, q1.y, q1.z, q1.w,
                       q2.x, q2.y, q2.z, q2.w, q3.x, q3.y, q3.z, q3.w,
                       q4.x, q4.y, q4.z, q4.w};
#pragma unroll
        for (int j = 0; j < 20; ++j) lv[j] = raw[j] - MINWL;
    } else {
#pragma unroll
        for (int j = 0; j < 20; ++j) lv[j] = -1;
    }
    unsigned long long hA = 0, hB = 0;  // packed u16 histograms l=0..3 / l=4..6
#pragma unroll
    for (int j = 0; j < 20; ++j) {
        int l = lv[j];
        if (l >= 0) {
            int sh = (l & 3) * 16;
            unsigned long long inc = 1ULL << sh;
            bool isA = l < 4;
            hA += isA ? inc : 0ULL;
            hB += isA ? 0ULL : inc;
        }
    }
    int lane = t & 63, wv = t >> 6;
    unsigned long long iA = hA, iB = hB;
#pragma unroll
    for (int o = 1; o < 64; o <<= 1) {
        unsigned long long a2 = (unsigned long long)__shfl_up((long long)iA, o);
        unsigned long long b2 = (unsigned long long)__shfl_up((long long)iB, o);
        if (lane >= o) { iA += a2; iB += b2; }
    }
    __shared__ unsigned long long wA[8], wB[8];
    __shared__ int base_s[8];
    if (lane == 63) { wA[wv] = iA; wB[wv] = iB; }
    __syncthreads();
    unsigned long long pA = 0, pB = 0, tA = 0, tB = 0;
#pragma unroll
    for (int w2 = 0; w2 < 8; ++w2) {
        if (w2 < wv) { pA += wA[w2]; pB += wB[w2]; }
        tA += wA[w2]; tB += wB[w2];
    }
    unsigned long long eA = pA + iA - hA, eB = pB + iB - hB;  // exclusive prefix
    if (t == 0) {
        int tot[7] = {(int)(tA & 0xFFFF), (int)((tA >> 16) & 0xFFFF),
                      (int)((tA >> 32) & 0xFFFF), (int)((tA >> 48) & 0xFFFF),
                      (int)(tB & 0xFFFF), (int)((tB >> 16) & 0xFFFF),
                      (int)((tB >> 32) & 0xFFFF)};
        int run = 0;
        for (int l = 0; l < 7; ++l) { base_s[l] = run; bases[l] = run; run += tot[l]; }
        base_s[7] = run; bases[7] = run;
    }
    __syncthreads();
    unsigned long long qA = eA + ((unsigned long long)base_s[0] |
                                  ((unsigned long long)base_s[1] << 16) |
                                  ((unsigned long long)base_s[2] << 32) |
                                  ((unsigned long long)base_s[3] << 48));
    unsigned long long qB = eB + ((unsigned long long)base_s[4] |
                                  ((unsigned long long)base_s[5] << 16) |
                                  ((unsigned long long)base_s[6] << 32));
#pragma unroll
    for (int j = 0; j < 20; ++j) {  // stable: ascending v within thread
        int l = lv[j];
        if (l >= 0) {
            int sh = (l & 3) * 16;
            bool isA = l < 4;
            unsigned long long cur = isA ? qA : qB;
            int pos = (int)((cur >> sh) & 0xFFFF);
            origv[pos] = t * 20 + j;
            unsigned long long inc = 1ULL << sh;
            qA += isA ? inc : 0ULL;
            qB += isA ? 0ULL : inc;
        }
    }
}

// ========== kernel 1: dual-role — sim tiles (blk<512) + seg gather/pack (else) ==========
#define SSTR 260
#define SIM_LDS_BYTES ((2 * 32 * SSTR + 64) * 4)

__global__ __launch_bounds__(256) void k_simgather(const float* __restrict__ word,
                                                   const float* __restrict__ unit,
                                                   float* __restrict__ sim,
                                                   const int* __restrict__ origv,
                                                   const int* __restrict__ seg,
                                                   unsigned int* __restrict__ segP) {
    int blk = blockIdx.x;
    int t = threadIdx.x;
    if (blk >= 512) {  // gather role: pack sorted seg rows as u16
        int i = (blk - 512) * 256 + t;
        if (i < NV) {
            int v = origv[i];
            const int2* sp = (const int2*)(seg + v * MAXWL);
            int2 a0 = sp[0], a1 = sp[1], a2 = sp[2], a3 = sp[3], a4 = sp[4];
            unsigned int* dst = segP + i * 8;
            *(uint4*)dst = make_uint4((unsigned)(a0.x | (a0.y << 16)),
                                      (unsigned)(a1.x | (a1.y << 16)),
                                      (unsigned)(a2.x | (a2.y << 16)),
                                      (unsigned)(a3.x | (a3.y << 16)));
            dst[4] = (unsigned)(a4.x | (a4.y << 16));
        }
        return;
    }
    extern __shared__ float lds[];
    float* wt = lds;
    float* ut = lds + 32 * SSTR;
    float* scaleW = lds + 64 * SSTR;
    float* scaleU = scaleW + 32;
    int uc = blk & 15, lt = (blk >> 4) & 1, b = blk >> 5;
    int l0 = lt * 32, u0 = uc * 32;

#pragma unroll
    for (int i = 0; i < 32; ++i)
        wt[i * SSTR + t] = word[(b * NL + l0 + i) * ND + t];
#pragma unroll
    for (int i = 0; i < 32; ++i) {
        int u = u0 + i;
        ut[i * SSTR + t] = (u < NU) ? unit[u * ND + t] : 1.0f;
    }
    __syncthreads();
#pragma unroll
    for (int h = 0; h < 2; ++h) {
        int r = (t >> 4) + h * 16, p = t & 15;
        float sw = 0.f, su = 0.f;
#pragma unroll
        for (int c = 0; c < 16; ++c) {
            float x = wt[r * SSTR + p * 16 + c];
            float y = ut[r * SSTR + p * 16 + c];
            sw += x * x; su += y * y;
        }
#pragma unroll
        for (int o = 1; o < 16; o <<= 1) {
            sw += __shfl_xor(sw, o);
            su += __shfl_xor(su, o);
        }
        if (p == 0) { scaleW[r] = 1.0f / sqrtf(sw); scaleU[r] = 1.0f / sqrtf(su); }
    }
    __syncthreads();

    int lane = t & 15;
    int lp = t >> 4;
    int l = lp * 2;
    const float4* w0p = (const float4*)(wt + l * SSTR);
    const float4* w1p = (const float4*)(wt + (l + 1) * SSTR);
    const float4* x0p = (const float4*)(ut + lane * SSTR);
    const float4* x1p = (const float4*)(ut + (lane + 16) * SSTR);
    float a00 = 0.f, a01 = 0.f, a10 = 0.f, a11 = 0.f;
#pragma unroll 8
    for (int dq = 0; dq < ND / 4; ++dq) {
        float4 w0 = w0p[dq], w1 = w1p[dq], x0 = x0p[dq], x1 = x1p[dq];
        a00 += w0.x * x0.x + w0.y * x0.y + w0.z * x0.z + w0.w * x0.w;
        a01 += w0.x * x1.x + w0.y * x1.y + w0.z * x1.z + w0.w * x1.w;
        a10 += w1.x * x0.x + w1.y * x0.y + w1.z * x0.z + w1.w * x0.w;
        a11 += w1.x * x1.x + w1.y * x1.y + w1.z * x1.z + w1.w * x1.w;
    }
    float sw0 = scaleW[l], sw1 = scaleW[l + 1];
    float su0 = scaleU[lane], su1 = scaleU[lane + 16];
    int gu0 = u0 + lane, gu1 = u0 + lane + 16;
    int base = (b * NL + l0 + l) * NU;
    if (gu0 < NU) { sim[base + gu0] = a00 * (sw0 * su0); sim[base + NU + gu0] = a10 * (sw1 * su0); }
    if (gu1 < NU) { sim[base + gu1] = a01 * (sw0 * su1); sim[base + NU + gu1] = a11 * (sw1 * su1); }
}

// ========== kernel 2: transposed soft-min — all-LDS main loop (R10 verbatim) ==========

template <int L>
__device__ __forceinline__ void item_one(const unsigned int* __restrict__ segL,
                                         int li, const float* __restrict__ dl,
                                         const int* __restrict__ rowoff,
                                         float& Sb, float& Wb, float& mb, int& ixb,
                                         float& Sm, float& Wm, float& mmv, int& ixm) {
    const unsigned int* sp = segL + li * 8;
    uint4 p = *(const uint4*)sp;                    // uniform b128
    unsigned int w4 = (L > 8) ? sp[4] : 0u;          // uniform b32 (L=9,10 only)
    unsigned int c[10];
    c[0] = p.x & 0xFFFF; c[1] = p.x >> 16;
    c[2] = p.y & 0xFFFF; c[3] = p.y >> 16;
    c[4] = p.z & 0xFFFF; c[5] = p.z >> 16;
    c[6] = p.w & 0xFFFF; c[7] = p.w >> 16;
    c[8] = w4 & 0xFFFF;  c[9] = w4 >> 16;
    float q = ((dl[rowoff[0] + c[0]] + dl[rowoff[1] + c[1]]) +
               dl[rowoff[2] + c[2]]) + dl[rowoff[3] + c[3]];
    float pm = q;
#pragma unroll
    for (int j = 4; j < L; ++j) {
        if (j == L - 1) pm = q;  // pref(L-1)
        q += dl[rowoff[j] + c[j]];
    }
    float wb = __builtin_amdgcn_exp2f(fmaf(q, -L2I, (float)L * L2I));
    Sb += wb;
    Wb = fmaf(q, wb, Wb);
    bool lb = q < mb;
    ixb = lb ? li : ixb;
    mb = lb ? q : mb;
    if constexpr (L >= 5) {  // k = L-5: ed = pref(L-1)+1, anchor L-1
        float edm = pm + 1.0f;
        float wm = __builtin_amdgcn_exp2f(fmaf(edm, -L2I, (float)(L - 1) * L2I));
        Sm += wm;
        Wm = fmaf(edm, wm, Wm);
        bool lm = edm < mmv;
        ixm = lm ? li : ixm;
        mmv = lm ? edm : mmv;
    }
}

template <int L>
__device__ __forceinline__ void bucket_passL(int a, int e, int gofs,
                                             const unsigned int* __restrict__ segL,
                                             const float* __restrict__ dl,
                                             const int* __restrict__ rowoff,
                                             float* m, float* S, float* W, int* ix) {
    if (a >= e) return;
    float Sb = 0.f, Wb = 0.f, mb = 3.0e38f;
    float Sm = 0.f, Wm = 0.f, mmv = 3.0e38f;
    int ixb = 0, ixm = 0;
    int li = a;
    for (; li + 1 < e; li += 2) {  // 2-item unroll (R10-proven: VGPR stays sane)
        item_one<L>(segL, li, dl, rowoff, Sb, Wb, mb, ixb, Sm, Wm, mmv, ixm);
        item_one<L>(segL, li + 1, dl, rowoff, Sb, Wb, mb, ixb, Sm, Wm, mmv, ixm);
    }
    if (li < e)
        item_one<L>(segL, li, dl, rowoff, Sb, Wb, mb, ixb, Sm, Wm, mmv, ixm);

    int gb = ixb + gofs, gm_ = ixm + gofs;  // local -> global sorted index
#pragma unroll
    for (int k = 0; k < NWL; ++k) {
        if (k >= L - 4) {
            float c = (float)(k + 4 - L);
            S[k] += Sb;
            W[k] += fmaf(c, Sb, Wb);
            float cand = mb + c;  // same float op as reference's q+(float)penalty
            bool take = (cand < m[k]) || (cand == m[k] && gb < ix[k]);
            ix[k] = take ? gb : ix[k];
            m[k] = take ? cand : m[k];
        }
        if constexpr (L >= 5) {
            if (k == L - 5) {
                S[k] += Sm;
                W[k] += Wm;
                bool take = (mmv < m[k]) || (mmv == m[k] && gm_ < ix[k]);
                ix[k] = take ? gm_ : ix[k];
                m[k] = take ? mmv : m[k];
            }
        }
    }
}

__global__ __launch_bounds__(NTX, 1) void k_extract(const float* __restrict__ sim,
                                                    const unsigned int* __restrict__ segP,
                                                    const int* __restrict__ basesG,
                                                    float* __restrict__ pM,
                                                    float* __restrict__ pS,
                                                    float* __restrict__ pW,
                                                    int* __restrict__ pI) {
    extern __shared__ float dl[];  // [65][RSTR] then segL
    unsigned int* segL = (unsigned int*)(dl + DLPAD);
    int blk = blockIdx.x;          // b*NCH + ch
    int ch = blk & (NCH - 1), b = blk >> 4;
    int t = threadIdx.x;
    int s = t & 63, w = t >> 6;    // w in 0..15

    // block-level bucket slices + local LDS bases
    int cs[7], ne[7], lb[7];
    {
        int run = 0;
#pragma unroll
        for (int l = 0; l < 7; ++l) {
            int lo = basesG[l], hi = basesG[l + 1];
            int n = hi - lo;
            int pc = (n + NCH - 1) >> 4;
            int c0 = lo + ch * pc;
            int c1 = min(c0 + pc, hi);
            cs[l] = c0;
            ne[l] = max(c1 - c0, 0);
            lb[l] = run;
            run += ne[l];
        }
    }

    // stage d = 1 - sim (rows 0..63) + zero row 64
    {
        const float2* simq = (const float2*)(sim + b * NL * NU);
        for (int idx = t; idx < NL * 250; idx += NTX) {
            int r = idx / 250;
            int u2 = idx - r * 250;
            float2 g = simq[idx];
            float* ds = dl + r * RSTR + u2 * 2;
            ds[0] = 1.0f - g.x;
            ds[1] = 1.0f - g.y;
        }
        if (t < NU + 1) dl[64 * RSTR + t] = 0.0f;
    }
    // stage packed seg rows for this block's 7 ranges
#pragma unroll
    for (int l = 0; l < 7; ++l) {
        for (int ii = t; ii < ne[l]; ii += NTX) {
            const unsigned int* gp = segP + (cs[l] + ii) * 8;
            uint4 pv = *(const uint4*)gp;
            unsigned int w4 = gp[4];
            unsigned int* dp = segL + (lb[l] + ii) * 8;
            *(uint4*)dp = pv;
            dp[4] = w4;
        }
    }
    __syncthreads();

    int rowoff[10];
#pragma unroll
    for (int j = 0; j < 10; ++j) rowoff[j] = min(s + j, 64) * RSTR;

    float m[NWL], S[NWL], W[NWL];
    int ix[NWL];
#pragma unroll
    for (int k = 0; k < NWL; ++k) { m[k] = 3.0e38f; S[k] = 0.f; W[k] = 0.f; ix[k] = 0; }

    int la[7], le[7];
#pragma unroll
    for (int l = 0; l < 7; ++l) {
        int pw = (ne[l] + NWAVES - 1) >> 4;
        la[l] = lb[l] + w * pw;
        le[l] = min(la[l] + pw, lb[l] + ne[l]);
    }
    bucket_passL<4>(la[0], le[0], cs[0] - lb[0], segL, dl, rowoff, m, S, W, ix);
    bucket_passL<5>(la[1], le[1], cs[1] - lb[1], segL, dl, rowoff, m, S, W, ix);
    bucket_passL<6>(la[2], le[2], cs[2] - lb[2], segL, dl, rowoff, m, S, W, ix);
    bucket_passL<7>(la[3], le[3], cs[3] - lb[3], segL, dl, rowoff, m, S, W, ix);
    bucket_passL<8>(la[4], le[4], cs[4] - lb[4], segL, dl, rowoff, m, S, W, ix);
    bucket_passL<9>(la[5], le[5], cs[5] - lb[5], segL, dl, rowoff, m, S, W, ix);
    bucket_passL<10>(la[6], le[6], cs[6] - lb[6], segL, dl, rowoff, m, S, W, ix);

    // cross-wave merge via LDS (dl/segL dead now); 16 partial sets = 114.7KB
    __syncthreads();
    float* scrM = dl;                        // [16][NWL][64]
    float* scrS = dl + NWAVES * NSK;
    float* scrW = dl + 2 * NWAVES * NSK;
    int* scrI = (int*)(dl + 3 * NWAVES * NSK);
#pragma unroll
    for (int k = 0; k < NWL; ++k) {
        int o = (w * NWL + k) * 64 + s;
        scrM[o] = m[k]; scrS[o] = S[k]; scrW[o] = W[k]; scrI[o] = ix[k];
    }
    __syncthreads();
    if (t < NSK) {
        int k = t >> 6, ss = t & 63;
        int o0 = k * 64 + ss;
        float mm = scrM[o0], SS = scrS[o0], WW = scrW[o0];
        int II = scrI[o0];
#pragma unroll
        for (int w2 = 1; w2 < NWAVES; ++w2) {
            int o = (w2 * NWL + k) * 64 + ss;
            float m2 = scrM[o];
            int i2 = scrI[o];
            bool take = (m2 < mm) || (m2 == mm && i2 < II);
            II = take ? i2 : II;
            mm = take ? m2 : mm;
            SS += scrS[o];
            WW += scrW[o];
        }
        int off = (b * NCH + ch) * NSK + t;
        pM[off] = mm; pS[off] = SS; pW[off] = WW; pI[off] = II;
    }
}

// ========== kernel 3: merge chunks, scores, dense, span softmax, outputs ==========
__global__ __launch_bounds__(NT) void k_merge(const float* __restrict__ pM,
                                              const float* __restrict__ pS,
                                              const float* __restrict__ pW,
                                              const int* __restrict__ pI,
                                              const int* __restrict__ origv,
                                              float* __restrict__ out) {
    int b = blockIdx.x, t = threadIdx.x;
    __shared__ float score[NSK];
    __shared__ int ixf[NSK];
    __shared__ float rm[8], rS[8], rW[8];
    __shared__ int rX[8];
    __shared__ float gm;
    __shared__ int gfl;

    float x = -1.0f;  // invalid marker (valid scores are strictly > 0)
    int fl = 0x7FFFFFFF;
    if (t < NSK) {
        int base = b * NCH * NSK + t;
        float mm = pM[base], SS = pS[base], WW = pW[base];
        int II = pI[base];
        for (int c = 1; c < NCH; ++c) {
            int o = base + c * NSK;
            float m2 = pM[o];
            int i2 = pI[o];
            bool take = (m2 < mm) || (m2 == mm && i2 < II);
            II = take ? i2 : II;
            mm = take ? m2 : mm;
            SS += pS[o];
            WW += pW[o];
        }
        int k = t >> 6, ss = t & 63;
        int kmax = min(NWL - 1, 60 - ss);  // negative for ss > 60
        if (k <= kmax) {
            float med = WW / SS;
            float wl = (float)(MINWL + k);
            float z = 1.0f - 2.0f * (med / wl);
            float cel = (z > 0.f) ? z : (__expf(z) - 1.0f);  // celu
            x = 0.5f * (cel + 1.0f) * wl;
            ixf[t] = II;
            fl = ss * 64 + (ss + k + 3);  // flat dense index
        }
        score[t] = (k <= kmax) ? x : 0.0f;
    }
    __syncthreads();

    // block argmax (first flat index on ties)
    float mv = x;
    int mf = fl;
#pragma unroll
    for (int o = 32; o >= 1; o >>= 1) {
        float m2 = __shfl_down(mv, o);
        int f2 = __shfl_down(mf, o);
        bool take = (m2 > mv) || (m2 == mv && f2 < mf);
        mv = take ? m2 : mv;
        mf = take ? f2 : mf;
    }
    if ((t & 63) == 0) { rm[t >> 6] = mv; rX[t >> 6] = mf; }
    __syncthreads();
    if (t == 0) {
        float mm = rm[0];
        int ff = rX[0];
#pragma unroll
        for (int w2 = 1; w2 < 8; ++w2) {
            bool take = (rm[w2] > mm) || (rm[w2] == mm && rX[w2] < ff);
            mm = take ? rm[w2] : mm;
            ff = take ? rX[w2] : ff;
        }
        gm = mm; gfl = ff;
    }
    __syncthreads();
    float M = gm;

    // soft-max sums over the 406 candidates + closed-form zero mass
    float Sl = 0.f, Wl = 0.f;
    if (x >= 0.0f) {
        float wq = __expf((x - M) * ITEMP);
        Sl = wq;
        Wl = x * wq;
    }
#pragma unroll
    for (int o = 32; o >= 1; o >>= 1) {
        Sl += __shfl_down(Sl, o);
        Wl += __shfl_down(Wl, o);
    }
    if ((t & 63) == 0) { rS[t >> 6] = Sl; rW[t >> 6] = Wl; }
    __syncthreads();
    if (t == 0) {
        float SS = 0.f, WW = 0.f;
#pragma unroll
        for (int w2 = 0; w2 < 8; ++w2) { SS += rS[w2]; WW += rW[w2]; }
        SS += NZERO * __expf(-M * ITEMP);  // zero cells' mass (W contribution is 0)
        float best = WW / SS;
        int st = gfl >> 6, en = gfl & 63;
        int ks = en - st - 3;  // winner is always a viable cell -> 0..6
        int II = ixf[ks * 64 + st];
        out[b] = (float)st;
        out[NB + b] = (float)en;
        out[2 * NB + b] = best;
        out[3 * NB + b] = (float)origv[II];
    }

    // dense output
    float* dense = out + 4 * NB + b * NL * NL;
    for (int f = t; f < NL * NL; f += NT) {
        int ss = f >> 6, ee = f & 63;
        int k = ee - ss - 3;
        dense[f] = (k >= 0 && k < NWL) ? score[k * 64 + ss] : 0.0f;
    }
}

extern "C" void kernel_launch(void* const* d_in, const int* in_sizes, int n_in,
                              void* d_out, int out_size, void* d_ws, size_t ws_size,
                              hipStream_t stream) {
    const float* word = (const float*)d_in[0];  // (B,L,D) f32
    const float* unit = (const float*)d_in[1];  // (U,D) f32
    const int* seg = (const int*)d_in[2];       // (V,MAXWL) i32
    const int* vlen = (const int*)d_in[3];      // (V,) i32
    float* out = (float*)d_out;                 // [start|end|score|vocab|dense]
    char* ws = (char*)d_ws;
    float* sim = (float*)ws;                    // 2,048,000 B
    int* origv = (int*)(ws + 2048000);          // 40,000 B
    int* bases = (int*)(ws + 2088000);          // 32 B
    unsigned int* segP = (unsigned int*)(ws + 2088032);  // 320,000 B
    float* pM = (float*)(ws + 2408032);         // 458,752 B each
    float* pS = (float*)(ws + 2866784);
    float* pW = (float*)(ws + 3325536);
    int* pI = (int*)(ws + 3784288);

    hipFuncSetAttribute((const void*)k_simgather,
                        hipFuncAttributeMaxDynamicSharedMemorySize, SIM_LDS_BYTES);
    hipFuncSetAttribute((const void*)k_extract,
                        hipFuncAttributeMaxDynamicSharedMemorySize, EXT_LDS_BYTES);

    k_sort<<<1, 512, 0, stream>>>(vlen, origv, bases);
    k_simgather<<<512 + 40, 256, SIM_LDS_BYTES, stream>>>(word, unit, sim,
                                                          origv, seg, segP);
    k_extract<<<NB * NCH, NTX, EXT_LDS_BYTES, stream>>>(sim, segP, bases, pM, pS, pW, pI);
    k_merge<<<NB, NT, 0, stream>>>(pM, pS, pW, pI, origv, out);
}